// Round 1
// baseline (140.075 us; speedup 1.0000x reference)
//
#include <hip/hip_runtime.h>
#include <hip/hip_bf16.h>
#include <stdint.h>

// ZoeDepth attractor head, fused: GEMM1(bf16 MFMA) -> relu -> GEMM2(bf16 MFMA)
// -> softplus -> exp-attractor over 64 bins -> duplicated output.
//
// Sizes (hardcoded from setup_inputs): n=4, c=256, h*w=16384, mlp=128,
// n_attractors=16, n_bins=64.

#define HW 16384
#define ALPHA 300.0f

typedef short bf16x8_t __attribute__((ext_vector_type(8)));
typedef float f32x4_t __attribute__((ext_vector_type(4)));
typedef unsigned int u32x4_t __attribute__((ext_vector_type(4)));

__device__ __forceinline__ unsigned short f2bf(float f) {
  // round-to-nearest-even fp32 -> bf16 (no NaN handling needed here)
  unsigned int u = __builtin_bit_cast(unsigned int, f);
  u += 0x7fffu + ((u >> 16) & 1u);
  return (unsigned short)(u >> 16);
}
__device__ __forceinline__ unsigned int pack2(float a, float b) {
  return (unsigned int)f2bf(a) | ((unsigned int)f2bf(b) << 16);
}

// ---------------------------------------------------------------------------
// Prep kernel: convert w1 (128x256) and w2 (16x128) fp32 -> bf16 blobs in ws,
// laid out as the LDS tile format: chunks of [rows][32 cols], 16B granules
// XOR-swizzled by (row&3). w1 blob: 8 chunks x 8192 B at offset 0.
// w2 blob: 4 chunks x 1024 B at half-offset 32768 (byte 65536).
// ---------------------------------------------------------------------------
__global__ void zoed_prep(const float* __restrict__ w1,
                          const float* __restrict__ w2,
                          unsigned short* __restrict__ blob) {
  int i = blockIdx.x * 256 + threadIdx.x;  // 136*256 = 34816 = 32768 + 2048
  if (i < 32768) {
    int o = i >> 8, c = i & 255;
    float v = w1[i];
    int idx = (c >> 5) * 4096 + o * 32 + ((((c >> 3) & 3) ^ (o & 3)) << 3) + (c & 7);
    blob[idx] = f2bf(v);
  } else {
    int i2 = i - 32768;
    int a = i2 >> 7, o = i2 & 127;
    float v = w2[i2];
    int idx = 32768 + (o >> 5) * 512 + a * 32 + ((((o >> 3) & 3) ^ (a & 3)) << 3) + (o & 7);
    blob[idx] = f2bf(v);
  }
}

// ---------------------------------------------------------------------------
// Fused main kernel. Grid: 512 blocks (4 n * 128 pixel-tiles of 128), 256 thr.
// ---------------------------------------------------------------------------
__global__ __launch_bounds__(256, 2) void zoed_fused(
    const float* __restrict__ x, const float* __restrict__ bprev,
    const float* __restrict__ b1, const float* __restrict__ b2,
    const unsigned short* __restrict__ wblob, float* __restrict__ out) {
  // LDS: phase1: xbuf 8K @0, w1buf 8K @8192.  phase2: hid 32K @0 (overlay),
  // Albuf 8K @32768, w2buf 4K @40960.  total 44 KiB.
  __shared__ __align__(16) char smem[45056];
  char* xbuf = smem;
  char* w1buf = smem + 8192;
  char* hid = smem;
  char* Albuf = smem + 32768;
  char* w2buf = smem + 40960;

  const int t = threadIdx.x;
  const int lane = t & 63;
  const int l15 = lane & 15;
  const int quad = lane >> 4;
  const int wv = t >> 6;
  const int wm = wv & 1;        // wave row (o 0..64 / 64..128)
  const int wn = wv >> 1;       // wave col (p 0..64 / 64..128)
  const int sw = ((quad ^ (lane & 3)) << 4);  // swizzled granule byte offset

  const int blk = blockIdx.x;
  const int n = blk >> 7;
  const int p0 = (blk & 127) << 7;

  // copy w2 blob -> LDS (4096 B, one pass)
  *(u32x4_t*)(w2buf + t * 16) =
      *(const u32x4_t*)((const char*)wblob + 65536 + t * 16);

  f32x4_t acc[4][4];
#pragma unroll
  for (int i = 0; i < 4; i++)
#pragma unroll
    for (int j = 0; j < 4; j++) acc[i][j] = (f32x4_t){0.f, 0.f, 0.f, 0.f};

  const int sp = t & 127;   // staging row (pixel)
  const int sg = t >> 7;    // staging granule base {0,1}

  for (int kb = 0; kb < 8; ++kb) {
    __syncthreads();  // previous iter's LDS readers done
    // --- stage x chunk: 32 c x 128 p fp32 -> bf16, transposed to [p][c] ---
#pragma unroll
    for (int gi = 0; gi < 2; ++gi) {
      int g = sg + gi * 2;
      const float* xs = x + (size_t)(n * 256 + kb * 32 + g * 8) * HW + p0 + sp;
      float f0 = xs[0 * HW], f1 = xs[1 * HW], f2 = xs[2 * HW], f3 = xs[3 * HW];
      float f4 = xs[4 * HW], f5 = xs[5 * HW], f6 = xs[6 * HW], f7 = xs[7 * HW];
      u32x4_t v = {pack2(f0, f1), pack2(f2, f3), pack2(f4, f5), pack2(f6, f7)};
      *(u32x4_t*)(xbuf + sp * 64 + ((g ^ (sp & 3)) << 4)) = v;
    }
    // --- stage w1 chunk: raw 8192 B copy of pre-swizzled blob ---
    {
      const char* src = (const char*)wblob + kb * 8192 + t * 32;
      *(u32x4_t*)(w1buf + t * 32) = *(const u32x4_t*)src;
      *(u32x4_t*)(w1buf + t * 32 + 16) = *(const u32x4_t*)(src + 16);
    }
    __syncthreads();
    // --- fragments + 16 MFMAs ---
    bf16x8_t af[4], bfm[4];
#pragma unroll
    for (int tm = 0; tm < 4; tm++)
      af[tm] = *(const bf16x8_t*)(w1buf + (wm * 64 + tm * 16 + l15) * 64 + sw);
#pragma unroll
    for (int tn = 0; tn < 4; tn++)
      bfm[tn] = *(const bf16x8_t*)(xbuf + (wn * 64 + tn * 16 + l15) * 64 + sw);
#pragma unroll
    for (int tm = 0; tm < 4; tm++)
#pragma unroll
      for (int tn = 0; tn < 4; tn++)
        acc[tm][tn] = __builtin_amdgcn_mfma_f32_16x16x32_bf16(
            af[tm], bfm[tn], acc[tm][tn], 0, 0, 0);
  }

  __syncthreads();  // xbuf/w1buf readers done; hid overlay is now safe
  // --- hidden epilogue: relu(acc + b1) -> bf16 -> hid (T-chunks [p][o]) ---
#pragma unroll
  for (int tm = 0; tm < 4; tm++) {
    f32x4_t b1v = *(const f32x4_t*)(b1 + wm * 64 + tm * 16 + quad * 4);
    int kc = wm * 2 + (tm >> 1);
    int g = (tm & 1) * 2 + (quad >> 1);
    int off8 = (quad & 1) * 8;
#pragma unroll
    for (int tn = 0; tn < 4; tn++) {
      f32x4_t h = acc[tm][tn] + b1v;
      h[0] = fmaxf(h[0], 0.f);
      h[1] = fmaxf(h[1], 0.f);
      h[2] = fmaxf(h[2], 0.f);
      h[3] = fmaxf(h[3], 0.f);
      int prow = wn * 64 + tn * 16 + l15;
      unsigned int* dst = (unsigned int*)(hid + kc * 8192 + prow * 64 +
                                          ((g ^ (prow & 3)) << 4) + off8);
      dst[0] = pack2(h[0], h[1]);
      dst[1] = pack2(h[2], h[3]);
    }
  }
  __syncthreads();
  // --- GEMM2: A(16 x p) = softplus(w2 @ hidden + b2) ---
  bf16x8_t a2[4];
#pragma unroll
  for (int kc = 0; kc < 4; kc++)
    a2[kc] = *(const bf16x8_t*)(w2buf + kc * 1024 + l15 * 64 + sw);
  f32x4_t acc2[2];
  acc2[0] = (f32x4_t){0.f, 0.f, 0.f, 0.f};
  acc2[1] = (f32x4_t){0.f, 0.f, 0.f, 0.f};
#pragma unroll
  for (int tn = 0; tn < 2; tn++) {
    int prow = wv * 32 + tn * 16 + l15;
#pragma unroll
    for (int kc = 0; kc < 4; kc++) {
      bf16x8_t bh = *(const bf16x8_t*)(hid + kc * 8192 + prow * 64 + sw);
      acc2[tn] = __builtin_amdgcn_mfma_f32_16x16x32_bf16(a2[kc], bh, acc2[tn],
                                                         0, 0, 0);
    }
  }
  f32x4_t b2v = *(const f32x4_t*)(b2 + quad * 4);
#pragma unroll
  for (int tn = 0; tn < 2; tn++) {
    f32x4_t z = acc2[tn] + b2v;
    f32x4_t spv;
#pragma unroll
    for (int r = 0; r < 4; r++) {
      float zz = z[r];
      spv[r] = fmaxf(zz, 0.f) + log1pf(__expf(-fabsf(zz)));  // stable softplus
    }
    int prow = wv * 32 + tn * 16 + l15;
    *(f32x4_t*)(Albuf + prow * 64 + ((quad ^ (prow & 3)) << 4)) = spv;
  }
  __syncthreads();
  // --- attractor stage: per pixel, 16 attractors x 32 bins per thread ---
  {
    const int p = t & 127;
    const int half = t >> 7;
    float Av[16];
#pragma unroll
    for (int q = 0; q < 4; q++) {
      f32x4_t v = *(const f32x4_t*)(Albuf + p * 64 + ((q ^ (p & 3)) << 4));
      Av[q * 4 + 0] = v[0];
      Av[q * 4 + 1] = v[1];
      Av[q * 4 + 2] = v[2];
      Av[q * 4 + 3] = v[3];
    }
    size_t base = (size_t)n * 64 * HW + (size_t)(half * 32) * HW + (size_t)(p0 + p);
    const float* bp = bprev + base;
    float* o1 = out + base;
    float* o2 = out + (size_t)4 * 64 * HW + base;
#pragma unroll 4
    for (int b = 0; b < 32; b++) {
      float c = bp[(size_t)b * HW];
      float d0 = 0.f, d1 = 0.f;
#pragma unroll
      for (int a = 0; a < 8; a++) {
        float dx = Av[a] - c;
        float e = __expf(dx * dx * -ALPHA);
        d0 = fmaf(e, dx, d0);
      }
#pragma unroll
      for (int a = 8; a < 16; a++) {
        float dx = Av[a] - c;
        float e = __expf(dx * dx * -ALPHA);
        d1 = fmaf(e, dx, d1);
      }
      float r = c + (d0 + d1);
      __builtin_nontemporal_store(r, o1 + (size_t)b * HW);
      __builtin_nontemporal_store(r, o2 + (size_t)b * HW);
    }
  }
}

extern "C" void kernel_launch(void* const* d_in, const int* in_sizes, int n_in,
                              void* d_out, int out_size, void* d_ws,
                              size_t ws_size, hipStream_t stream) {
  const float* x = (const float*)d_in[0];      // 4*256*128*128
  const float* bprev = (const float*)d_in[1];  // 4*64*128*128
  const float* w1 = (const float*)d_in[2];     // 128*256
  const float* b1 = (const float*)d_in[3];     // 128
  const float* w2 = (const float*)d_in[4];     // 16*128
  const float* b2 = (const float*)d_in[5];     // 16
  float* outp = (float*)d_out;                 // 2 * 4194304
  unsigned short* blob = (unsigned short*)d_ws;  // 69632 B used

  zoed_prep<<<136, 256, 0, stream>>>(w1, w2, blob);
  zoed_fused<<<512, 256, 0, stream>>>(x, bprev, b1, b2, blob, outp);
}

// Round 2
// 136.753 us; speedup vs baseline: 1.0243x; 1.0243x over previous
//
#include <hip/hip_runtime.h>
#include <hip/hip_bf16.h>
#include <stdint.h>

// ZoeDepth attractor head, fused: GEMM1(bf16 MFMA) -> relu -> GEMM2(bf16 MFMA)
// -> softplus -> exp-attractor over 64 bins -> duplicated output.
// R1: 64-px tiles (grid 1024, 4 blocks/CU), register prefetch across the
// K-loop barriers, 24 KiB LDS.

#define HW 16384
#define ALPHA 300.0f

typedef short bf16x8_t __attribute__((ext_vector_type(8)));
typedef float f32x4_t __attribute__((ext_vector_type(4)));
typedef unsigned int u32x4_t __attribute__((ext_vector_type(4)));

__device__ __forceinline__ unsigned short f2bf(float f) {
  unsigned int u = __builtin_bit_cast(unsigned int, f);
  u += 0x7fffu + ((u >> 16) & 1u);
  return (unsigned short)(u >> 16);
}
__device__ __forceinline__ unsigned int pack2(float a, float b) {
  return (unsigned int)f2bf(a) | ((unsigned int)f2bf(b) << 16);
}

// ---------------------------------------------------------------------------
// Prep: w1 (128x256) and w2 (16x128) fp32 -> bf16 blobs, LDS tile format,
// 16B granules XOR-swizzled by (row&3). w1: 8 chunks x 8192 B @0.
// w2: 4 chunks x 1024 B @byte 65536.
// ---------------------------------------------------------------------------
__global__ void zoed_prep(const float* __restrict__ w1,
                          const float* __restrict__ w2,
                          unsigned short* __restrict__ blob) {
  int i = blockIdx.x * 256 + threadIdx.x;  // 136*256 = 34816 = 32768 + 2048
  if (i < 32768) {
    int o = i >> 8, c = i & 255;
    float v = w1[i];
    int idx = (c >> 5) * 4096 + o * 32 + ((((c >> 3) & 3) ^ (o & 3)) << 3) + (c & 7);
    blob[idx] = f2bf(v);
  } else {
    int i2 = i - 32768;
    int a = i2 >> 7, o = i2 & 127;
    float v = w2[i2];
    int idx = 32768 + (o >> 5) * 512 + a * 32 + ((((o >> 3) & 3) ^ (a & 3)) << 3) + (o & 7);
    blob[idx] = f2bf(v);
  }
}

// ---------------------------------------------------------------------------
// Fused main kernel. Grid: 1024 blocks (4 n * 256 pixel-tiles of 64), 256 thr.
// ---------------------------------------------------------------------------
__global__ __launch_bounds__(256, 4) void zoed_fused(
    const float* __restrict__ x, const float* __restrict__ bprev,
    const float* __restrict__ b1, const float* __restrict__ b2,
    const unsigned short* __restrict__ wblob, float* __restrict__ out) {
  // Phase1: xbuf 4K @0, w1buf 8K @4096.
  // Phase2: hid 16K @0 (overlay), Albuf 4K @16384, w2buf 4K @20480.
  __shared__ __align__(16) char smem[24576];
  char* xbuf = smem;
  char* w1buf = smem + 4096;
  char* hid = smem;
  char* Albuf = smem + 16384;
  char* w2buf = smem + 20480;

  const int t = threadIdx.x;
  const int lane = t & 63;
  const int l15 = lane & 15;
  const int quad = lane >> 4;
  const int wv = t >> 6;
  const int wm = wv & 1;   // o half (0..64 / 64..128)
  const int wn = wv >> 1;  // p half (0..32 / 32..64)
  const int sw = ((quad ^ (lane & 3)) << 4);

  const int blk = blockIdx.x;
  const int n = blk >> 8;
  const int p0 = (blk & 255) << 6;

  // w2 blob -> LDS (4096 B)
  *(u32x4_t*)(w2buf + t * 16) =
      *(const u32x4_t*)((const char*)wblob + 65536 + t * 16);

  f32x4_t acc[4][2];
#pragma unroll
  for (int i = 0; i < 4; i++)
#pragma unroll
    for (int j = 0; j < 2; j++) acc[i][j] = (f32x4_t){0.f, 0.f, 0.f, 0.f};

  const int sp = t & 63;  // staging pixel row
  const int sg = t >> 6;  // staging channel granule 0..3

  // ---- prefetch chunk 0 ----
  const float* xsbase = x + (size_t)(n * 256 + sg * 8) * HW + p0 + sp;
  float xf0, xf1, xf2, xf3, xf4, xf5, xf6, xf7;
  u32x4_t wfa, wfb;
  {
    const float* xs = xsbase;
    xf0 = xs[0 * HW]; xf1 = xs[1 * HW]; xf2 = xs[2 * HW]; xf3 = xs[3 * HW];
    xf4 = xs[4 * HW]; xf5 = xs[5 * HW]; xf6 = xs[6 * HW]; xf7 = xs[7 * HW];
    const char* wsrc = (const char*)wblob + t * 32;
    wfa = *(const u32x4_t*)wsrc;
    wfb = *(const u32x4_t*)(wsrc + 16);
  }

  for (int kb = 0; kb < 8; ++kb) {
    __syncthreads();  // previous iter's LDS readers done
    // ---- store prefetched chunk into LDS ----
    {
      u32x4_t v = {pack2(xf0, xf1), pack2(xf2, xf3), pack2(xf4, xf5),
                   pack2(xf6, xf7)};
      *(u32x4_t*)(xbuf + sp * 64 + ((sg ^ (sp & 3)) << 4)) = v;
      *(u32x4_t*)(w1buf + t * 32) = wfa;
      *(u32x4_t*)(w1buf + t * 32 + 16) = wfb;
    }
    __syncthreads();
    // ---- issue next chunk's global loads (overlap with MFMA below) ----
    if (kb < 7) {
      const float* xs = xsbase + (size_t)((kb + 1) * 32) * HW;
      xf0 = xs[0 * HW]; xf1 = xs[1 * HW]; xf2 = xs[2 * HW]; xf3 = xs[3 * HW];
      xf4 = xs[4 * HW]; xf5 = xs[5 * HW]; xf6 = xs[6 * HW]; xf7 = xs[7 * HW];
      const char* wsrc = (const char*)wblob + (kb + 1) * 8192 + t * 32;
      wfa = *(const u32x4_t*)wsrc;
      wfb = *(const u32x4_t*)(wsrc + 16);
    }
    // ---- fragments + 8 MFMAs ----
    bf16x8_t af[4], bfm[2];
#pragma unroll
    for (int tm = 0; tm < 4; tm++)
      af[tm] = *(const bf16x8_t*)(w1buf + (wm * 64 + tm * 16 + l15) * 64 + sw);
#pragma unroll
    for (int tn = 0; tn < 2; tn++)
      bfm[tn] = *(const bf16x8_t*)(xbuf + (wn * 32 + tn * 16 + l15) * 64 + sw);
#pragma unroll
    for (int tm = 0; tm < 4; tm++)
#pragma unroll
      for (int tn = 0; tn < 2; tn++)
        acc[tm][tn] = __builtin_amdgcn_mfma_f32_16x16x32_bf16(
            af[tm], bfm[tn], acc[tm][tn], 0, 0, 0);
  }

  __syncthreads();  // xbuf/w1buf frag reads done; hid overlay safe
  // ---- hidden epilogue: relu(acc + b1) -> bf16 -> hid chunks [p][o] ----
#pragma unroll
  for (int tm = 0; tm < 4; tm++) {
    f32x4_t b1v = *(const f32x4_t*)(b1 + wm * 64 + tm * 16 + quad * 4);
    int kc = wm * 2 + (tm >> 1);
    int g = (tm & 1) * 2 + (quad >> 1);
    int off8 = (quad & 1) * 8;
#pragma unroll
    for (int tn = 0; tn < 2; tn++) {
      f32x4_t h = acc[tm][tn] + b1v;
      h[0] = fmaxf(h[0], 0.f);
      h[1] = fmaxf(h[1], 0.f);
      h[2] = fmaxf(h[2], 0.f);
      h[3] = fmaxf(h[3], 0.f);
      int prow = wn * 32 + tn * 16 + l15;
      unsigned int* dst = (unsigned int*)(hid + kc * 4096 + prow * 64 +
                                          ((g ^ (prow & 3)) << 4) + off8);
      dst[0] = pack2(h[0], h[1]);
      dst[1] = pack2(h[2], h[3]);
    }
  }
  __syncthreads();
  // ---- GEMM2: A(16 x 64px) = softplus(w2 @ hidden + b2); 1 p-tile/wave ----
  {
    f32x4_t acc2 = (f32x4_t){0.f, 0.f, 0.f, 0.f};
    const int prow = wv * 16 + l15;
#pragma unroll
    for (int kc = 0; kc < 4; kc++) {
      bf16x8_t a2 = *(const bf16x8_t*)(w2buf + kc * 1024 + l15 * 64 + sw);
      bf16x8_t bh = *(const bf16x8_t*)(hid + kc * 4096 + prow * 64 + sw);
      acc2 = __builtin_amdgcn_mfma_f32_16x16x32_bf16(a2, bh, acc2, 0, 0, 0);
    }
    f32x4_t b2v = *(const f32x4_t*)(b2 + quad * 4);
    f32x4_t z = acc2 + b2v;
    f32x4_t spv;
#pragma unroll
    for (int r = 0; r < 4; r++) {
      float zz = z[r];
      spv[r] = fmaxf(zz, 0.f) + log1pf(__expf(-fabsf(zz)));  // stable softplus
    }
    *(f32x4_t*)(Albuf + prow * 64 + ((quad ^ (prow & 3)) << 4)) = spv;
  }
  __syncthreads();
  // ---- attractor: px = t&63, 16 bins per thread (grp = t>>6) ----
  {
    const int p = t & 63;
    const int grp = t >> 6;
    float Av[16];
#pragma unroll
    for (int q = 0; q < 4; q++) {
      f32x4_t v = *(const f32x4_t*)(Albuf + p * 64 + ((q ^ (p & 3)) << 4));
      Av[q * 4 + 0] = v[0];
      Av[q * 4 + 1] = v[1];
      Av[q * 4 + 2] = v[2];
      Av[q * 4 + 3] = v[3];
    }
    size_t base = (size_t)n * 64 * HW + (size_t)(grp * 16) * HW + (size_t)(p0 + p);
    const float* bp = bprev + base;
    float* o1 = out + base;
    float* o2 = out + (size_t)4 * 64 * HW + base;
#pragma unroll 4
    for (int b = 0; b < 16; b++) {
      float c = bp[(size_t)b * HW];
      float d0 = 0.f, d1 = 0.f;
#pragma unroll
      for (int a = 0; a < 8; a++) {
        float dx = Av[a] - c;
        float e = __expf(dx * dx * -ALPHA);
        d0 = fmaf(e, dx, d0);
      }
#pragma unroll
      for (int a = 8; a < 16; a++) {
        float dx = Av[a] - c;
        float e = __expf(dx * dx * -ALPHA);
        d1 = fmaf(e, dx, d1);
      }
      float r = c + (d0 + d1);
      __builtin_nontemporal_store(r, o1 + (size_t)b * HW);
      __builtin_nontemporal_store(r, o2 + (size_t)b * HW);
    }
  }
}

extern "C" void kernel_launch(void* const* d_in, const int* in_sizes, int n_in,
                              void* d_out, int out_size, void* d_ws,
                              size_t ws_size, hipStream_t stream) {
  const float* x = (const float*)d_in[0];      // 4*256*128*128
  const float* bprev = (const float*)d_in[1];  // 4*64*128*128
  const float* w1 = (const float*)d_in[2];     // 128*256
  const float* b1 = (const float*)d_in[3];     // 128
  const float* w2 = (const float*)d_in[4];     // 16*128
  const float* b2 = (const float*)d_in[5];     // 16
  float* outp = (float*)d_out;                 // 2 * 4194304
  unsigned short* blob = (unsigned short*)d_ws;  // 69632 B used

  zoed_prep<<<136, 256, 0, stream>>>(w1, w2, blob);
  zoed_fused<<<1024, 256, 0, stream>>>(x, bprev, b1, b2, blob, outp);
}

// Round 3
// 133.889 us; speedup vs baseline: 1.0462x; 1.0214x over previous
//
#include <hip/hip_runtime.h>
#include <hip/hip_bf16.h>
#include <stdint.h>

// ZoeDepth attractor head, fused. R2: deep MLP — distance-4 rolling register
// prefetch for x, w1/w2 fragments read directly from pre-swizzled L2-hot blob,
// single-barrier LDS double-buffer, fully unrolled attractor with pre-issued
// bprev loads. 20 KiB LDS.

#define HW 16384
#define ALPHA 300.0f

typedef short bf16x8_t __attribute__((ext_vector_type(8)));
typedef float f32x4_t __attribute__((ext_vector_type(4)));
typedef unsigned int u32x4_t __attribute__((ext_vector_type(4)));

__device__ __forceinline__ unsigned short f2bf(float f) {
  unsigned int u = __builtin_bit_cast(unsigned int, f);
  u += 0x7fffu + ((u >> 16) & 1u);
  return (unsigned short)(u >> 16);
}
__device__ __forceinline__ unsigned int pack2(float a, float b) {
  return (unsigned int)f2bf(a) | ((unsigned int)f2bf(b) << 16);
}

// ---------------------------------------------------------------------------
// Prep: w1 (128x256) and w2 (16x128) fp32 -> bf16 blobs in frag layout,
// 16B granules XOR-swizzled by (row&3). w1: 8 chunks x 8192 B @0.
// w2: 4 chunks x 1024 B @byte 65536.
// ---------------------------------------------------------------------------
__global__ void zoed_prep(const float* __restrict__ w1,
                          const float* __restrict__ w2,
                          unsigned short* __restrict__ blob) {
  int i = blockIdx.x * 256 + threadIdx.x;  // 136*256 = 34816 = 32768 + 2048
  if (i < 32768) {
    int o = i >> 8, c = i & 255;
    float v = w1[i];
    int idx = (c >> 5) * 4096 + o * 32 + ((((c >> 3) & 3) ^ (o & 3)) << 3) + (c & 7);
    blob[idx] = f2bf(v);
  } else {
    int i2 = i - 32768;
    int a = i2 >> 7, o = i2 & 127;
    float v = w2[i2];
    int idx = 32768 + (o >> 5) * 512 + a * 32 + ((((o >> 3) & 3) ^ (a & 3)) << 3) + (o & 7);
    blob[idx] = f2bf(v);
  }
}

// ---------------------------------------------------------------------------
// Fused main kernel. Grid: 1024 blocks (4 n * 256 pixel-tiles of 64), 256 thr.
// ---------------------------------------------------------------------------
__global__ __launch_bounds__(256, 4) void zoed_fused(
    const float* __restrict__ x, const float* __restrict__ bprev,
    const float* __restrict__ b1, const float* __restrict__ b2,
    const unsigned short* __restrict__ wblob, float* __restrict__ out) {
  // LDS: phase1: x dbuf 2 x 4K @0.  phase2: hid 16K @0 (overlay),
  // Albuf 4K @16384.  total 20 KiB.
  __shared__ __align__(16) char smem[20480];
  char* hid = smem;
  char* Albuf = smem + 16384;

  const int t = threadIdx.x;
  const int lane = t & 63;
  const int l15 = lane & 15;
  const int quad = lane >> 4;
  const int wv = t >> 6;
  const int wm = wv & 1;   // o half (0..64 / 64..128)
  const int wn = wv >> 1;  // p half (0..32 / 32..64)
  const int sw = ((quad ^ (lane & 3)) << 4);

  const int blk = blockIdx.x;
  const int n = blk >> 8;
  const int p0 = (blk & 255) << 6;

  const int sp = t & 63;  // staging pixel row
  const int sg = t >> 6;  // staging channel granule 0..3

  // ---- pre-issue x chunks 0..3 (32 loads outstanding) ----
  const float* xsbase = x + (size_t)(n * 256 + sg * 8) * HW + p0 + sp;
  float xr[4][8];
#pragma unroll
  for (int c = 0; c < 4; c++)
#pragma unroll
    for (int j = 0; j < 8; j++)
      xr[c][j] = xsbase[(size_t)(c * 32 + j) * HW];

  // ---- pre-issue w1 frags for chunk 0 (direct from L2-hot blob) ----
  const char* wbase = (const char*)wblob + (wm * 64 + l15) * 64 + sw;
  bf16x8_t afn[4];
#pragma unroll
  for (int tm = 0; tm < 4; tm++)
    afn[tm] = *(const bf16x8_t*)(wbase + tm * 1024);

  f32x4_t acc[4][2];
#pragma unroll
  for (int i = 0; i < 4; i++)
#pragma unroll
    for (int j = 0; j < 2; j++) acc[i][j] = (f32x4_t){0.f, 0.f, 0.f, 0.f};

#pragma unroll
  for (int kb = 0; kb < 8; ++kb) {
    char* xb = smem + (kb & 1) * 4096;
    // current w1 frags; issue next chunk's
    bf16x8_t afc[4];
#pragma unroll
    for (int tm = 0; tm < 4; tm++) afc[tm] = afn[tm];
    if (kb < 7) {
#pragma unroll
      for (int tm = 0; tm < 4; tm++)
        afn[tm] = *(const bf16x8_t*)(wbase + (kb + 1) * 8192 + tm * 1024);
    }
    // pack chunk kb -> LDS dbuf
    {
      u32x4_t v = {pack2(xr[kb & 3][0], xr[kb & 3][1]),
                   pack2(xr[kb & 3][2], xr[kb & 3][3]),
                   pack2(xr[kb & 3][4], xr[kb & 3][5]),
                   pack2(xr[kb & 3][6], xr[kb & 3][7])};
      *(u32x4_t*)(xb + sp * 64 + ((sg ^ (sp & 3)) << 4)) = v;
    }
    // refill slot with chunk kb+4 (keeps 24-32 loads in flight)
    if (kb < 4) {
#pragma unroll
      for (int j = 0; j < 8; j++)
        xr[kb & 3][j] = xsbase[(size_t)((kb + 4) * 32 + j) * HW];
    }
    __syncthreads();
    // fragments + 8 MFMAs
    bf16x8_t bfm[2];
#pragma unroll
    for (int tn = 0; tn < 2; tn++)
      bfm[tn] = *(const bf16x8_t*)(xb + (wn * 32 + tn * 16 + l15) * 64 + sw);
#pragma unroll
    for (int tm = 0; tm < 4; tm++)
#pragma unroll
      for (int tn = 0; tn < 2; tn++)
        acc[tm][tn] = __builtin_amdgcn_mfma_f32_16x16x32_bf16(
            afc[tm], bfm[tn], acc[tm][tn], 0, 0, 0);
  }

  // ---- pre-issue bprev loads (16) and w2 frags (4) for later phases ----
  const int ap = t & 63;
  const int grp = t >> 6;
  size_t obase = (size_t)n * 64 * HW + (size_t)(grp * 16) * HW + (size_t)(p0 + ap);
  const float* bp = bprev + obase;
  float bpr[16];
#pragma unroll
  for (int b = 0; b < 16; b++) bpr[b] = bp[(size_t)b * HW];
  bf16x8_t a2[4];
#pragma unroll
  for (int kc = 0; kc < 4; kc++)
    a2[kc] = *(const bf16x8_t*)((const char*)wblob + 65536 + kc * 1024 +
                                l15 * 64 + sw);

  __syncthreads();  // last frag reads done; hid overlay safe
  // ---- hidden epilogue: relu(acc + b1) -> bf16 -> hid chunks [p][o] ----
#pragma unroll
  for (int tm = 0; tm < 4; tm++) {
    f32x4_t b1v = *(const f32x4_t*)(b1 + wm * 64 + tm * 16 + quad * 4);
    int kc = wm * 2 + (tm >> 1);
    int g = (tm & 1) * 2 + (quad >> 1);
    int off8 = (quad & 1) * 8;
#pragma unroll
    for (int tn = 0; tn < 2; tn++) {
      f32x4_t h = acc[tm][tn] + b1v;
      h[0] = fmaxf(h[0], 0.f);
      h[1] = fmaxf(h[1], 0.f);
      h[2] = fmaxf(h[2], 0.f);
      h[3] = fmaxf(h[3], 0.f);
      int prow = wn * 32 + tn * 16 + l15;
      unsigned int* dst = (unsigned int*)(hid + kc * 4096 + prow * 64 +
                                          ((g ^ (prow & 3)) << 4) + off8);
      dst[0] = pack2(h[0], h[1]);
      dst[1] = pack2(h[2], h[3]);
    }
  }
  __syncthreads();
  // ---- GEMM2: A(16 x 64px) = softplus(w2 @ hidden + b2); 1 p-tile/wave ----
  {
    f32x4_t acc2 = (f32x4_t){0.f, 0.f, 0.f, 0.f};
    const int prow = wv * 16 + l15;
#pragma unroll
    for (int kc = 0; kc < 4; kc++) {
      bf16x8_t bh = *(const bf16x8_t*)(hid + kc * 4096 + prow * 64 + sw);
      acc2 = __builtin_amdgcn_mfma_f32_16x16x32_bf16(a2[kc], bh, acc2, 0, 0, 0);
    }
    f32x4_t b2v = *(const f32x4_t*)(b2 + quad * 4);
    f32x4_t z = acc2 + b2v;
    f32x4_t spv;
#pragma unroll
    for (int r = 0; r < 4; r++) {
      float zz = z[r];
      spv[r] = fmaxf(zz, 0.f) + log1pf(__expf(-fabsf(zz)));  // stable softplus
    }
    *(f32x4_t*)(Albuf + prow * 64 + ((quad ^ (prow & 3)) << 4)) = spv;
  }
  __syncthreads();
  // ---- attractor: px = t&63, 16 bins per thread, fully unrolled ----
  {
    float Av[16];
#pragma unroll
    for (int q = 0; q < 4; q++) {
      f32x4_t v = *(const f32x4_t*)(Albuf + ap * 64 + ((q ^ (ap & 3)) << 4));
      Av[q * 4 + 0] = v[0];
      Av[q * 4 + 1] = v[1];
      Av[q * 4 + 2] = v[2];
      Av[q * 4 + 3] = v[3];
    }
    float* o1 = out + obase;
    float* o2 = out + (size_t)4 * 64 * HW + obase;
#pragma unroll
    for (int b = 0; b < 16; b++) {
      float c = bpr[b];
      float d0 = 0.f, d1 = 0.f;
#pragma unroll
      for (int a = 0; a < 8; a++) {
        float dx = Av[a] - c;
        float e = __expf(dx * dx * -ALPHA);
        d0 = fmaf(e, dx, d0);
      }
#pragma unroll
      for (int a = 8; a < 16; a++) {
        float dx = Av[a] - c;
        float e = __expf(dx * dx * -ALPHA);
        d1 = fmaf(e, dx, d1);
      }
      float r = c + (d0 + d1);
      __builtin_nontemporal_store(r, o1 + (size_t)b * HW);
      __builtin_nontemporal_store(r, o2 + (size_t)b * HW);
    }
  }
}

extern "C" void kernel_launch(void* const* d_in, const int* in_sizes, int n_in,
                              void* d_out, int out_size, void* d_ws,
                              size_t ws_size, hipStream_t stream) {
  const float* x = (const float*)d_in[0];      // 4*256*128*128
  const float* bprev = (const float*)d_in[1];  // 4*64*128*128
  const float* w1 = (const float*)d_in[2];     // 128*256
  const float* b1 = (const float*)d_in[3];     // 128
  const float* w2 = (const float*)d_in[4];     // 16*128
  const float* b2 = (const float*)d_in[5];     // 16
  float* outp = (float*)d_out;                 // 2 * 4194304
  unsigned short* blob = (unsigned short*)d_ws;  // 69632 B used

  zoed_prep<<<136, 256, 0, stream>>>(w1, w2, blob);
  zoed_fused<<<1024, 256, 0, stream>>>(x, bprev, b1, b2, blob, outp);
}